// Round 13
// baseline (184902.551 us; speedup 1.0000x reference)
//
#include <hip/hip_runtime.h>

// LSTMDynamics v13 — fp32-OUTPUT hypothesis test on the proven-executing
// zero-communication structure.
// B=64, T=512, D_IN=64, H=512, D_OUT=32. fp32 inputs, fp32 OUTPUT (new).
// One kernel, 64 blocks (one per batch sample) x 1024 threads; the whole
// 2-layer x 512-step recurrence runs in LDS. No workspace, no memset, no
// inter-block traffic, no marker, no diagnostics.

#define T13   512
#define H13   512
#define DIN13 64

__device__ inline float sig13(float x) { return 1.f / (1.f + __expf(-x)); }
__device__ inline float tanh13(float x) {
    if (x >  9.f) return  1.f;
    if (x < -9.f) return -1.f;
    const float e = __expf(2.f * x);
    return (e - 1.f) / (e + 1.f);
}
__device__ inline float4 ldg4_13(const float* p) { return *(const float4*)p; }
__device__ inline float dot4_13(float4 a, float4 b) {
    return a.x * b.x + a.y * b.y + a.z * b.z + a.w * b.w;
}

// Grid: 64 blocks x 1024 threads. Thread t computes gate-rows {t, t+1024}
// of the 2048 preactivations (rows 0..511=i, 512..1023=f, 1024..1535=g,
// 1536..2047=o — PyTorch gate order, matching the reference's split).
__global__ __launch_bounds__(1024) void lstm_batch_v13(
    const float* __restrict__ x,
    const float* __restrict__ Wih0, const float* __restrict__ Whh0,
    const float* __restrict__ bih0, const float* __restrict__ bhh0,
    const float* __restrict__ Wih1, const float* __restrict__ Whh1,
    const float* __restrict__ bih1, const float* __restrict__ bhh1,
    const float* __restrict__ Wout, const float* __restrict__ bout,
    float* __restrict__ out)                       // fp32 OUTPUT
{
    const int b = blockIdx.x;       // batch sample
    const int t = threadIdx.x;      // 0..1023

    __shared__ __align__(16) float h0[H13];
    __shared__ __align__(16) float c0[H13];
    __shared__ __align__(16) float h1[H13];
    __shared__ __align__(16) float c1[H13];
    __shared__ __align__(16) float pre[2048];
    __shared__ __align__(16) float xs[DIN13];
    __shared__ float red[1024];

    if (t < H13) { h0[t] = 0.f; c0[t] = 0.f; h1[t] = 0.f; c1[t] = 0.f; }
    __syncthreads();

    // Loop-invariant combined biases for this thread's two gate-rows.
    const float bias00 = bih0[t] + bhh0[t];
    const float bias01 = bih0[t + 1024] + bhh0[t + 1024];
    const float bias10 = bih1[t] + bhh1[t];
    const float bias11 = bih1[t + 1024] + bhh1[t + 1024];

    const float* wx0 = Wih0 + t * DIN13;
    const float* wx1 = Wih0 + (t + 1024) * DIN13;
    const float* wh0 = Whh0 + t * H13;
    const float* wh1 = Whh0 + (t + 1024) * H13;
    const float* v00 = Wih1 + t * H13;
    const float* v01 = Wih1 + (t + 1024) * H13;
    const float* u10 = Whh1 + t * H13;
    const float* u11 = Whh1 + (t + 1024) * H13;

    for (int s = 0; s < T13; ++s) {
        if (t < DIN13) xs[t] = x[(b * T13 + s) * DIN13 + t];
        __syncthreads();

        // ---- layer 0 ----
        float a0 = bias00, a1 = bias01;
        #pragma unroll
        for (int k = 0; k < DIN13; k += 4) {
            const float4 xv = *(const float4*)(xs + k);
            a0 += dot4_13(xv, ldg4_13(wx0 + k));
            a1 += dot4_13(xv, ldg4_13(wx1 + k));
        }
        #pragma unroll 4
        for (int k = 0; k < H13; k += 4) {
            const float4 hv = *(const float4*)(h0 + k);   // LDS broadcast
            a0 += dot4_13(hv, ldg4_13(wh0 + k));
            a1 += dot4_13(hv, ldg4_13(wh1 + k));
        }
        pre[t] = a0;
        pre[t + 1024] = a1;
        __syncthreads();
        if (t < H13) {
            const float ig = sig13(pre[t]);
            const float fg = sig13(pre[t + 512]);
            const float gg = tanh13(pre[t + 1024]);
            const float og = sig13(pre[t + 1536]);
            const float cn = fg * c0[t] + ig * gg;
            c0[t] = cn;
            h0[t] = og * tanh13(cn);
        }
        __syncthreads();

        // ---- layer 1 ----
        float d0 = bias10, d1 = bias11;
        #pragma unroll 4
        for (int k = 0; k < H13; k += 4) {
            const float4 av = *(const float4*)(h0 + k);
            d0 += dot4_13(av, ldg4_13(v00 + k));
            d1 += dot4_13(av, ldg4_13(v01 + k));
        }
        #pragma unroll 4
        for (int k = 0; k < H13; k += 4) {
            const float4 bv = *(const float4*)(h1 + k);
            d0 += dot4_13(bv, ldg4_13(u10 + k));
            d1 += dot4_13(bv, ldg4_13(u11 + k));
        }
        pre[t] = d0;
        pre[t + 1024] = d1;
        __syncthreads();
        if (t < H13) {
            const float ig = sig13(pre[t]);
            const float fg = sig13(pre[t + 512]);
            const float gg = tanh13(pre[t + 1024]);
            const float og = sig13(pre[t + 1536]);
            const float cn = fg * c1[t] + ig * gg;
            c1[t] = cn;
            h1[t] = og * tanh13(cn);
        }
        __syncthreads();
    }

    // ---- epilogue: y[b][d] = h1 . Wout[d] + bout[d]; 32 threads per output ----
    {
        const int d = t >> 5;        // 0..31
        const int j = t & 31;        // 0..31
        float p = 0.f;
        const float* wb = Wout + d * H13 + j * 16;
        #pragma unroll
        for (int k = 0; k < 16; ++k) p += h1[j * 16 + k] * wb[k];
        red[t] = p;
        __syncthreads();
        #pragma unroll
        for (int off = 16; off > 0; off >>= 1) {
            if ((t & 31) < off) red[t] += red[t + off];
            __syncthreads();
        }
        if ((t & 31) == 0)
            out[b * 32 + d] = red[t] + bout[d];    // fp32 store, no marker
    }
}

extern "C" void kernel_launch(void* const* d_in, const int* in_sizes, int n_in,
                              void* d_out, int out_size, void* d_ws, size_t ws_size,
                              hipStream_t stream) {
    (void)in_sizes; (void)n_in; (void)out_size; (void)d_ws; (void)ws_size;
    const float* x    = (const float*)d_in[0];
    const float* Wih0 = (const float*)d_in[1];
    const float* Whh0 = (const float*)d_in[2];
    const float* bih0 = (const float*)d_in[3];
    const float* bhh0 = (const float*)d_in[4];
    const float* Wih1 = (const float*)d_in[5];
    const float* Whh1 = (const float*)d_in[6];
    const float* bih1 = (const float*)d_in[7];
    const float* bhh1 = (const float*)d_in[8];
    const float* Wout = (const float*)d_in[9];
    const float* bout = (const float*)d_in[10];

    lstm_batch_v13<<<dim3(64), dim3(1024), 0, stream>>>(
        x, Wih0, Whh0, bih0, bhh0, Wih1, Whh1, bih1, bhh1, Wout, bout,
        (float*)d_out);
}

// Round 14
// 14738.251 us; speedup vs baseline: 12.5458x; 12.5458x over previous
//
#include <hip/hip_runtime.h>

// LSTMDynamics v14: B=64, T=512, D_IN=64, H=512, D_OUT=32.
// fp32 inputs, fp32 OUTPUT (proven R13). Persistent fused 2-layer LSTM —
// the round-2 design (proven to execute & compute correct dynamics; only its
// bf16 output write was wrong) with fp32 rings + fp32 epilogue.
// 256 blocks x 256 threads (1 block/CU, co-resident; barrier proven live),
// layer skew: blocks 0..127 run layer0 step s, blocks 128..255 layer1 step s-1.
// Weights preloaded ONCE into fp16 MFMA B-fragments (registers) -> zero
// per-step weight traffic (kills R13's 31.6 GB re-stream). fp32 accumulate,
// fp32 cell state in registers, fp32 h double-buffer rings in ws.

#define T_    512
#define B_    64
#define H_    512
#define DIN_  64
#define NBLK  256
#define NTHR  256
#define SLOT  (B_ * H_)   // 32768 fp32 per ring slot, layout [b][k]

typedef _Float16 half8  __attribute__((ext_vector_type(8)));
typedef float    floatx4 __attribute__((ext_vector_type(4)));

__device__ inline float sigf(float x) { return 1.f / (1.f + __expf(-x)); }
__device__ inline float tanhf_(float x) {
    if (x >  9.f) return  1.f;
    if (x < -9.f) return -1.f;
    const float e = __expf(2.f * x);
    return (e - 1.f) / (e + 1.f);
}
__device__ inline float4 ld4(const float* p) { return *(const float4*)p; }

// fp32[8] -> fp16 MFMA fragment
__device__ inline half8 frag8(const float* p) {
    const float4 a = ld4(p), b = ld4(p + 4);
    half8 r;
    r[0] = (_Float16)a.x; r[1] = (_Float16)a.y; r[2] = (_Float16)a.z; r[3] = (_Float16)a.w;
    r[4] = (_Float16)b.x; r[5] = (_Float16)b.y; r[6] = (_Float16)b.z; r[7] = (_Float16)b.w;
    return r;
}

// Grid barrier — byte-for-byte the proven round-2 protocol.
__device__ inline void gsync(unsigned* bar, int step) {
    __syncthreads();
    if (threadIdx.x == 0) {
        __threadfence();
        unsigned t = atomicAdd(&bar[0], 1u);
        if (t == (unsigned)(NBLK - 1)) {
            atomicExch(&bar[0], 0u);
            __threadfence();
            atomicAdd(&bar[16], 1u);
        } else {
            while ((int)atomicAdd(&bar[16], 0u) <= step) __builtin_amdgcn_s_sleep(2);
        }
    }
    __syncthreads();
    __threadfence();
}

// MFMA 16x16x32 f16 fragment layout (proven by R2<->R5 bit-agreement):
//   A: a[j] = A[m = lane&15][k = (lane>>4)*8 + j]
//   B: b[j] = B[k = (lane>>4)*8 + j][n = lane&15]
//   D: d[r] = D[m = (lane>>4)*4 + r][n = lane&15]
__global__ __launch_bounds__(NTHR) void lstm_v14(
    const float* __restrict__ x,
    const float* __restrict__ Wih0, const float* __restrict__ Whh0,
    const float* __restrict__ bih0, const float* __restrict__ bhh0,
    const float* __restrict__ Wih1, const float* __restrict__ Whh1,
    const float* __restrict__ bih1, const float* __restrict__ bhh1,
    const float* __restrict__ Wout, const float* __restrict__ bout,
    float* __restrict__ out,
    unsigned* bar,
    float* ring0,       // 2 slots [64][512] fp32
    float* ring1)       // 2 slots [64][512] fp32
{
    const int tid   = threadIdx.x;
    const int wave  = tid >> 6;
    const int lane  = tid & 63;
    const int l15   = lane & 15;
    const int quad  = lane >> 4;
    const int blk   = blockIdx.x;
    const int layer = blk >> 7;        // 0: blocks 0..127, 1: blocks 128..255
    const int id    = blk & 127;
    const int mt    = id >> 5;         // batch tile (4 x 16)
    const int jt    = id & 31;         // column tile (32 x 16)

    __shared__ float red[3][4][4][64]; // partials from waves 1..3

    // Combined biases: wave0 lanes own column jt*16 + l15.
    float bsi = 0.f, bsf = 0.f, bsg = 0.f, bso = 0.f;
    if (wave == 0) {
        const int j = jt * 16 + l15;
        const float* bi = layer ? bih1 : bih0;
        const float* bh = layer ? bhh1 : bhh0;
        bsi = bi[j]        + bh[j];
        bsf = bi[512 + j]  + bh[512 + j];
        bsg = bi[1024 + j] + bh[1024 + j];
        bso = bi[1536 + j] + bh[1536 + j];
    }

    float cst[4] = {0.f, 0.f, 0.f, 0.f};  // cell state: 4 batch rows x 1 col / lane

    if (layer == 0) {
        // Layer 0: A = [x_t (K 0..63) | h0_{s-1} (K 64..575)], 18 chunks of 32.
        const int cstart = (wave < 2) ? wave * 5 : 10 + (wave - 2) * 4;
        const int cnt    = (wave < 2) ? 5 : 4;
        half8 bf[4][5];
        #pragma unroll
        for (int g = 0; g < 4; ++g) {
            const int n = g * 512 + jt * 16 + l15;   // gate row (i,f,g,o)
            #pragma unroll
            for (int cc = 0; cc < 5; ++cc) {
                if (cc < cnt) {
                    const int c = cstart + cc;
                    const float* src = (c < 2)
                        ? (Wih0 + n * 64  + c * 32 + quad * 8)
                        : (Whh0 + n * 512 + (c - 2) * 32 + quad * 8);
                    bf[g][cc] = frag8(src);
                }
            }
        }

        for (int s = 0; s <= T_; ++s) {
            const bool active = (s < T_);
            floatx4 acc[4] = { {0.f,0.f,0.f,0.f}, {0.f,0.f,0.f,0.f},
                               {0.f,0.f,0.f,0.f}, {0.f,0.f,0.f,0.f} };
            if (active) {
                const float* h0prev = ring0 + ((s + 1) & 1) * SLOT;  // slot (s-1)&1; s=0 -> zeros
                const int arow = mt * 16 + l15;
                #pragma unroll
                for (int cc = 0; cc < 5; ++cc) {
                    if (cc < cnt) {
                        const int c = cstart + cc;
                        half8 a;
                        if (c < 2) a = frag8(x + (arow * T_ + s) * DIN_ + c * 32 + quad * 8);
                        else       a = frag8(h0prev + arow * H_ + (c - 2) * 32 + quad * 8);
                        acc[0] = __builtin_amdgcn_mfma_f32_16x16x32_f16(a, bf[0][cc], acc[0], 0, 0, 0);
                        acc[1] = __builtin_amdgcn_mfma_f32_16x16x32_f16(a, bf[1][cc], acc[1], 0, 0, 0);
                        acc[2] = __builtin_amdgcn_mfma_f32_16x16x32_f16(a, bf[2][cc], acc[2], 0, 0, 0);
                        acc[3] = __builtin_amdgcn_mfma_f32_16x16x32_f16(a, bf[3][cc], acc[3], 0, 0, 0);
                    }
                }
                if (wave != 0) {
                    #pragma unroll
                    for (int g = 0; g < 4; ++g)
                        #pragma unroll
                        for (int r = 0; r < 4; ++r)
                            red[wave - 1][g][r][lane] = acc[g][r];
                }
            }
            __syncthreads();
            if (active && wave == 0) {
                #pragma unroll
                for (int g = 0; g < 4; ++g)
                    #pragma unroll
                    for (int r = 0; r < 4; ++r)
                        acc[g][r] += red[0][g][r][lane] + red[1][g][r][lane] + red[2][g][r][lane];
                float* hdst = ring0 + (s & 1) * SLOT;
                #pragma unroll
                for (int r = 0; r < 4; ++r) {
                    const float ig = sigf(acc[0][r] + bsi);
                    const float fg = sigf(acc[1][r] + bsf);
                    const float gg = tanhf_(acc[2][r] + bsg);
                    const float og = sigf(acc[3][r] + bso);
                    const float cn = fg * cst[r] + ig * gg;
                    cst[r] = cn;
                    hdst[(mt * 16 + quad * 4 + r) * H_ + jt * 16 + l15] = og * tanhf_(cn);
                }
            }
            gsync(bar, s);
        }
    } else {
        // Layer 1 at tau = s-1: A = [h0_tau (K 0..511) | h1_{tau-1} (K 512..1023)].
        half8 bf[4][8];
        #pragma unroll
        for (int g = 0; g < 4; ++g) {
            const int n = g * 512 + jt * 16 + l15;
            #pragma unroll
            for (int cc = 0; cc < 8; ++cc) {
                const int c = wave * 8 + cc;              // 0..31
                const float* src = (c < 16)
                    ? (Wih1 + n * 512 + c * 32 + quad * 8)
                    : (Whh1 + n * 512 + (c - 16) * 32 + quad * 8);
                bf[g][cc] = frag8(src);
            }
        }

        for (int s = 0; s <= T_; ++s) {
            const bool active = (s >= 1);
            const int tau = s - 1;
            floatx4 acc[4] = { {0.f,0.f,0.f,0.f}, {0.f,0.f,0.f,0.f},
                               {0.f,0.f,0.f,0.f}, {0.f,0.f,0.f,0.f} };
            if (active) {
                const float* h0cur  = ring0 + (tau & 1) * SLOT;        // h0_tau
                const float* h1prev = ring1 + ((tau + 1) & 1) * SLOT;  // h1_{tau-1}; tau=0 -> zeros
                const int arow = mt * 16 + l15;
                const float* rb0 = h0cur  + arow * H_;
                const float* rb1 = h1prev + arow * H_;
                #pragma unroll
                for (int cc = 0; cc < 8; ++cc) {
                    const int c = wave * 8 + cc;
                    const half8 a = (c < 16) ? frag8(rb0 + c * 32 + quad * 8)
                                             : frag8(rb1 + (c - 16) * 32 + quad * 8);
                    acc[0] = __builtin_amdgcn_mfma_f32_16x16x32_f16(a, bf[0][cc], acc[0], 0, 0, 0);
                    acc[1] = __builtin_amdgcn_mfma_f32_16x16x32_f16(a, bf[1][cc], acc[1], 0, 0, 0);
                    acc[2] = __builtin_amdgcn_mfma_f32_16x16x32_f16(a, bf[2][cc], acc[2], 0, 0, 0);
                    acc[3] = __builtin_amdgcn_mfma_f32_16x16x32_f16(a, bf[3][cc], acc[3], 0, 0, 0);
                }
                if (wave != 0) {
                    #pragma unroll
                    for (int g = 0; g < 4; ++g)
                        #pragma unroll
                        for (int r = 0; r < 4; ++r)
                            red[wave - 1][g][r][lane] = acc[g][r];
                }
            }
            __syncthreads();
            if (active && wave == 0) {
                #pragma unroll
                for (int g = 0; g < 4; ++g)
                    #pragma unroll
                    for (int r = 0; r < 4; ++r)
                        acc[g][r] += red[0][g][r][lane] + red[1][g][r][lane] + red[2][g][r][lane];
                float* hdst = ring1 + (tau & 1) * SLOT;
                #pragma unroll
                for (int r = 0; r < 4; ++r) {
                    const float ig = sigf(acc[0][r] + bsi);
                    const float fg = sigf(acc[1][r] + bsf);
                    const float gg = tanhf_(acc[2][r] + bsg);
                    const float og = sigf(acc[3][r] + bso);
                    const float cn = fg * cst[r] + ig * gg;
                    cst[r] = cn;
                    hdst[(mt * 16 + quad * 4 + r) * H_ + jt * 16 + l15] = og * tanhf_(cn);
                }
            }
            gsync(bar, s);
        }
    }

    // Epilogue: y[b][d] = h1_511[b][:] . Wout[d][:] + bout[d]  (fp32 out).
    // h1_511 = ring1 slot (511&1)=1 (fp32), published by the final gsync.
    {
        const float* h1fin = ring1 + SLOT;
        const int gid = blk * NTHR + tid;   // 0..65535
        const int o   = gid >> 5;           // 0..2047
        const int sub = gid & 31;
        const int ob  = o >> 5;
        const int od  = o & 31;
        float p = 0.f;
        const float* hb = h1fin + ob * H_ + sub * 16;
        const float* wb = Wout  + od * H_ + sub * 16;
        #pragma unroll
        for (int k = 0; k < 16; ++k) p += hb[k] * wb[k];
        p += __shfl_xor(p, 16);
        p += __shfl_xor(p, 8);
        p += __shfl_xor(p, 4);
        p += __shfl_xor(p, 2);
        p += __shfl_xor(p, 1);
        if (sub == 0) out[o] = p + bout[od];
    }
}

extern "C" void kernel_launch(void* const* d_in, const int* in_sizes, int n_in,
                              void* d_out, int out_size, void* d_ws, size_t ws_size,
                              hipStream_t stream) {
    (void)in_sizes; (void)n_in; (void)out_size; (void)ws_size;
    const float* x    = (const float*)d_in[0];
    const float* Wih0 = (const float*)d_in[1];
    const float* Whh0 = (const float*)d_in[2];
    const float* bih0 = (const float*)d_in[3];
    const float* bhh0 = (const float*)d_in[4];
    const float* Wih1 = (const float*)d_in[5];
    const float* Whh1 = (const float*)d_in[6];
    const float* bih1 = (const float*)d_in[7];
    const float* bhh1 = (const float*)d_in[8];
    const float* Wout = (const float*)d_in[9];
    const float* bout = (const float*)d_in[10];

    unsigned char* ws = (unsigned char*)d_ws;
    unsigned* bar = (unsigned*)ws;                      // 1 KB
    float* ring0  = (float*)(ws + 1024);                // 2 slots x 128 KB
    float* ring1  = (float*)(ws + 1024 + 2 * SLOT * 4); // 2 slots x 128 KB
    // Zero barrier + both rings (slot1 of each must read as h_{-1}=0).
    hipMemsetAsync(ws, 0, 1024 + 4 * SLOT * 4, stream);

    lstm_v14<<<dim3(NBLK), dim3(NTHR), 0, stream>>>(
        x, Wih0, Whh0, bih0, bhh0, Wih1, Whh1, bih1, bhh1, Wout, bout,
        (float*)d_out, bar, ring0, ring1);
}